// Round 3
// baseline (188.018 us; speedup 1.0000x reference)
//
#include <hip/hip_runtime.h>
#include <math.h>

#define NW   12
#define DIM  4096
#define TPB  256

__device__ __forceinline__ float2 cmul(float2 a, float2 b) {
    return make_float2(a.x * b.x - a.y * b.y, a.x * b.y + a.y * b.x);
}

// acc = sum_j c_j * x_j (complex), 4 terms, no arrays
__device__ __forceinline__ float2 cfma4(float2 c0, float2 x0, float2 c1, float2 x1,
                                        float2 c2, float2 x2, float2 c3, float2 x3) {
    float ax = 0.f, ay = 0.f;
    ax = fmaf(c0.x, x0.x, fmaf(-c0.y, x0.y, ax)); ay = fmaf(c0.x, x0.y, fmaf(c0.y, x0.x, ay));
    ax = fmaf(c1.x, x1.x, fmaf(-c1.y, x1.y, ax)); ay = fmaf(c1.x, x1.y, fmaf(c1.y, x1.x, ay));
    ax = fmaf(c2.x, x2.x, fmaf(-c2.y, x2.y, ax)); ay = fmaf(c2.x, x2.y, fmaf(c2.y, x2.x, ay));
    ax = fmaf(c3.x, x3.x, fmaf(-c3.y, x3.y, ax)); ay = fmaf(c3.x, x3.y, fmaf(c3.y, x3.x, ay));
    return make_float2(ax, ay);
}

// (a,b) <- M (a,b), complex 2x2
__device__ __forceinline__ void cgate(float2& a, float2& b,
        const float2 m00, const float2 m01, const float2 m10, const float2 m11) {
    float2 na, nb;
    na.x = fmaf(m00.x, a.x, fmaf(-m00.y, a.y, fmaf(m01.x, b.x, -m01.y * b.y)));
    na.y = fmaf(m00.x, a.y, fmaf( m00.y, a.x, fmaf(m01.x, b.y,  m01.y * b.x)));
    nb.x = fmaf(m10.x, a.x, fmaf(-m10.y, a.y, fmaf(m11.x, b.x, -m11.y * b.y)));
    nb.y = fmaf(m10.x, a.y, fmaf( m10.y, a.x, fmaf(m11.x, b.y,  m11.y * b.x)));
    a = na; b = nb;
}

// cross-lane xor exchange: DPP quad_perm for masks 1,2 (VALU pipe), shfl otherwise
template<int B>
__device__ __forceinline__ float shflx(float x) {
    if constexpr (B == 0) {
        int i = __float_as_int(x);
        return __int_as_float(__builtin_amdgcn_update_dpp(i, i, 0xB1, 0xF, 0xF, true)); // quad_perm 1,0,3,2
    } else if constexpr (B == 1) {
        int i = __float_as_int(x);
        return __int_as_float(__builtin_amdgcn_update_dpp(i, i, 0x4E, 0xF, 0xF, true)); // quad_perm 2,3,0,1
    } else {
        return __shfl_xor(x, 1 << B, 64);
    }
}

// gate M on register bit J (z bit 8+J): pure VALU
template<int J>
__device__ __forceinline__ void reg_gate(float2* v,
        const float2 m00, const float2 m01, const float2 m10, const float2 m11) {
#pragma unroll
    for (int m = 0; m < 8; ++m) {
        int r0 = ((m >> J) << (J + 1)) | (m & ((1 << J) - 1));
        cgate(v[r0], v[r0 | (1 << J)], m00, m01, m10, m11);
    }
}

// gate M on lane bit B (z bit B): cross-lane, no barrier
template<int B>
__device__ __forceinline__ void lane_gate(float2* v, int lane,
        const float2 m00, const float2 m01, const float2 m10, const float2 m11) {
    const bool hib = (lane >> B) & 1;
    const float cax = hib ? m11.x : m00.x, cay = hib ? m11.y : m00.y;
    const float cbx = hib ? m10.x : m01.x, cby = hib ? m10.y : m01.y;
#pragma unroll
    for (int r = 0; r < 16; ++r) {
        float px = shflx<B>(v[r].x);
        float py = shflx<B>(v[r].y);
        float nx = fmaf(cax, v[r].x, fmaf(-cay, v[r].y, fmaf(cbx, px, -cby * py)));
        float ny = fmaf(cax, v[r].y, fmaf( cay, v[r].x, fmaf(cbx, py,  cby * px)));
        v[r] = make_float2(nx, ny);
    }
}

// fused: gates on wave bits 6,7 (M on each) + Gray CNOT permutation new[z]=old[z^(z>>1)],
// one LDS round trip. NO local arrays / pointer selects (SROA-safe: R2's 280MB scratch bug).
__device__ __forceinline__ void exchange(float2* psis, float2* v, int tid, int wv, int gwoff,
        const float2 m00, const float2 m01, const float2 m10, const float2 m11) {
    __syncthreads();                 // protect prior readers of psis
#pragma unroll
    for (int r = 0; r < 16; ++r) psis[(r << 8) | tid] = v[r];
    __syncthreads();

    const int y6  = (wv ^ (wv >> 1)) & 1;      // g(z) bit6 (same for all r)
    const int y7A = (wv >> 1) & 1;             // g(z) bit7 for even r; odd r flips
    const float2 M7A0 = y7A ? m10 : m00, M7A1 = y7A ? m11 : m01;
    const float2 M7B0 = y7A ? m00 : m10, M7B1 = y7A ? m01 : m11;
    const float2 M60  = y6  ? m10 : m00, M61  = y6  ? m11 : m01;
    // scalar row coefficients (even r -> A, odd r -> B)
    const float2 a0 = cmul(M7A0, M60), a1 = cmul(M7A0, M61), a2 = cmul(M7A1, M60), a3 = cmul(M7A1, M61);
    const float2 c0 = cmul(M7B0, M60), c1 = cmul(M7B0, M61), c2 = cmul(M7B1, M60), c3 = cmul(M7B1, M61);

#pragma unroll
    for (int h = 0; h < 8; ++h) {
        const int re = h << 1;
        const int baseE = ((((re << 8) ^ (re << 7)) ^ gwoff) & ~0xC0);
        const int baseO = baseE ^ 0x100;       // odd r differs by bit8 after masking
        float2 e0 = psis[baseE],        e1 = psis[baseE | 0x40];
        float2 e2 = psis[baseE | 0x80], e3 = psis[baseE | 0xC0];
        v[re]     = cfma4(a0, e0, a1, e1, a2, e2, a3, e3);
        float2 o0 = psis[baseO],        o1 = psis[baseO | 0x40];
        float2 o2 = psis[baseO | 0x80], o3 = psis[baseO | 0xC0];
        v[re | 1] = cfma4(c0, o0, c1, o1, c2, o2, c3, o3);
    }
}

__global__ __launch_bounds__(TPB, 4)
void qmnist_kernel(const float* __restrict__ x,  const float* __restrict__ W1,
                   const float* __restrict__ b1, const float* __restrict__ ryp,
                   const float* __restrict__ rzp, const float* __restrict__ W2,
                   const float* __restrict__ b2, float* __restrict__ out) {
    __shared__ float2 psis[DIM];
    __shared__ float  wred[4 * NW];
    __shared__ float  encc[NW], encs[NW];
    __shared__ float  zfin[NW];

    const int tid  = threadIdx.x;
    const int blk  = blockIdx.x;
    const int lane = tid & 63;
    const int wave = tid >> 6;
    const int wv   = tid >> 6;                  // z bits 7:6
    const int gwoff = tid ^ (tid >> 1);         // Gray of low-8 index bits

    // ---------------- phase 0: feat = x[blk] @ W1^T + b1 -> encoding angles
    float acc[NW];
#pragma unroll
    for (int w = 0; w < NW; ++w) acc[w] = 0.f;
    const float* xrow = x + (size_t)blk * 784;
    for (int j = tid; j < 784; j += TPB) {
        float xv = xrow[j];
#pragma unroll
        for (int w = 0; w < NW; ++w)
            acc[w] = fmaf(xv, W1[w * 784 + j], acc[w]);
    }
#pragma unroll
    for (int w = 0; w < NW; ++w) {
        float s = acc[w];
        s += __shfl_down(s, 32);
        s += __shfl_down(s, 16);
        s += __shfl_down(s, 8);
        s += __shfl_down(s, 4);
        s += __shfl_down(s, 2);
        s += __shfl_down(s, 1);
        if (lane == 0) wred[wave * NW + w] = s;
    }
    __syncthreads();
    if (tid < NW) {
        float feat = wred[tid] + wred[NW + tid] + wred[2 * NW + tid] + wred[3 * NW + tid] + b1[tid];
        float a = tanhf(feat) * 3.14159265358979323846f;
        float h = 0.5f * a;
        encc[tid] = cosf(h);
        encs[tid] = sinf(h);
    }
    __syncthreads();

    // ---------------- init product state directly into registers
    // z = (r<<8) | tid ; z bit b <-> wire (11-b)
    float hi = 1.f;
#pragma unroll
    for (int b = 0; b < 8; ++b) {
        int w = 11 - b;
        hi *= ((tid >> b) & 1) ? encs[w] : encc[w];
    }
    float2 v[16];
#pragma unroll
    for (int r = 0; r < 16; ++r) {
        float f = hi;
        f *= (r & 1) ? encs[3] : encc[3];
        f *= (r & 2) ? encs[2] : encc[2];
        f *= (r & 4) ? encs[1] : encc[1];
        f *= (r & 8) ? encs[0] : encc[0];
        v[r] = make_float2(f, 0.f);
    }

    // ---------------- fused variational gate  M = RZ(rz) * RY(ry)
    const float ry = ryp[0], rz = rzp[0];
    const float c  = cosf(0.5f * ry), s  = sinf(0.5f * ry);
    const float zc = cosf(0.5f * rz), zs = sinf(0.5f * rz);
    const float2 m00 = make_float2( c * zc, -c * zs);
    const float2 m01 = make_float2(-s * zc,  s * zs);
    const float2 m10 = make_float2( s * zc,  s * zs);
    const float2 m11 = make_float2( c * zc,  c * zs);

    for (int layer = 0; layer < 3; ++layer) {
        // register-bit gates (z bits 8..11), pure VALU
        reg_gate<0>(v, m00, m01, m10, m11);
        reg_gate<1>(v, m00, m01, m10, m11);
        reg_gate<2>(v, m00, m01, m10, m11);
        reg_gate<3>(v, m00, m01, m10, m11);
        // lane-bit gates (z bits 0..5), DPP / shuffle, no barriers
        lane_gate<0>(v, lane, m00, m01, m10, m11);
        lane_gate<1>(v, lane, m00, m01, m10, m11);
        lane_gate<2>(v, lane, m00, m01, m10, m11);
        lane_gate<3>(v, lane, m00, m01, m10, m11);
        lane_gate<4>(v, lane, m00, m01, m10, m11);
        lane_gate<5>(v, lane, m00, m01, m10, m11);
        // wave-bit gates (z bits 6,7) + Gray permutation, one LDS round trip
        exchange(psis, v, tid, wv, gwoff, m00, m01, m10, m11);
    }

    // ---------------- measure <Z_w>; state is in registers
    float t_total = 0.f, sj0 = 0.f, sj1 = 0.f, sj2 = 0.f, sj3 = 0.f;
#pragma unroll
    for (int r = 0; r < 16; ++r) {
        float p = fmaf(v[r].x, v[r].x, v[r].y * v[r].y);
        t_total += p;
        if (r & 1) sj0 += p;   // z bit 8  -> wire 3
        if (r & 2) sj1 += p;   // z bit 9  -> wire 2
        if (r & 4) sj2 += p;   // z bit 10 -> wire 1
        if (r & 8) sj3 += p;   // z bit 11 -> wire 0
    }
    float contrib[NW];
    contrib[3] = t_total - 2.f * sj0;
    contrib[2] = t_total - 2.f * sj1;
    contrib[1] = t_total - 2.f * sj2;
    contrib[0] = t_total - 2.f * sj3;
#pragma unroll
    for (int b = 0; b < 8; ++b) {
        int w = 11 - b;                      // wires 11..4 from tid bits 0..7
        contrib[w] = ((tid >> b) & 1) ? -t_total : t_total;
    }
#pragma unroll
    for (int w = 0; w < NW; ++w) {
        float sv = contrib[w];
        sv += __shfl_down(sv, 32);
        sv += __shfl_down(sv, 16);
        sv += __shfl_down(sv, 8);
        sv += __shfl_down(sv, 4);
        sv += __shfl_down(sv, 2);
        sv += __shfl_down(sv, 1);
        if (lane == 0) wred[wave * NW + w] = sv;
    }
    __syncthreads();
    if (tid < NW)
        zfin[tid] = wred[tid] + wred[NW + tid] + wred[2 * NW + tid] + wred[3 * NW + tid];
    __syncthreads();

    // ---------------- head: out = z @ W2^T + b2
    if (tid < 10) {
        float o = b2[tid];
#pragma unroll
        for (int w = 0; w < NW; ++w)
            o = fmaf(zfin[w], W2[tid * NW + w], o);
        out[(size_t)blk * 10 + tid] = o;
    }
}

extern "C" void kernel_launch(void* const* d_in, const int* in_sizes, int n_in,
                              void* d_out, int out_size, void* d_ws, size_t ws_size,
                              hipStream_t stream) {
    const float* x   = (const float*)d_in[0];
    const float* W1  = (const float*)d_in[1];
    const float* b1  = (const float*)d_in[2];
    const float* ry  = (const float*)d_in[3];
    const float* rz  = (const float*)d_in[4];
    const float* W2  = (const float*)d_in[5];
    const float* b2  = (const float*)d_in[6];
    float* out = (float*)d_out;

    const int batch = in_sizes[0] / 784;   // 2048
    qmnist_kernel<<<batch, TPB, 0, stream>>>(x, W1, b1, ry, rz, W2, b2, out);
}

// Round 4
// 187.564 us; speedup vs baseline: 1.0024x; 1.0024x over previous
//
#include <hip/hip_runtime.h>
#include <math.h>

#define NW   12
#define DIM  4096
#define TPB  256

__device__ __forceinline__ float2 cmul(float2 a, float2 b) {
    return make_float2(a.x * b.x - a.y * b.y, a.x * b.y + a.y * b.x);
}

// acc = sum_j c_j * x_j (complex), 4 terms, no arrays
__device__ __forceinline__ float2 cfma4(float2 c0, float2 x0, float2 c1, float2 x1,
                                        float2 c2, float2 x2, float2 c3, float2 x3) {
    float ax = 0.f, ay = 0.f;
    ax = fmaf(c0.x, x0.x, fmaf(-c0.y, x0.y, ax)); ay = fmaf(c0.x, x0.y, fmaf(c0.y, x0.x, ay));
    ax = fmaf(c1.x, x1.x, fmaf(-c1.y, x1.y, ax)); ay = fmaf(c1.x, x1.y, fmaf(c1.y, x1.x, ay));
    ax = fmaf(c2.x, x2.x, fmaf(-c2.y, x2.y, ax)); ay = fmaf(c2.x, x2.y, fmaf(c2.y, x2.x, ay));
    ax = fmaf(c3.x, x3.x, fmaf(-c3.y, x3.y, ax)); ay = fmaf(c3.x, x3.y, fmaf(c3.y, x3.x, ay));
    return make_float2(ax, ay);
}

// (a,b) <- M (a,b), complex 2x2
__device__ __forceinline__ void cgate(float2& a, float2& b,
        const float2 m00, const float2 m01, const float2 m10, const float2 m11) {
    float2 na, nb;
    na.x = fmaf(m00.x, a.x, fmaf(-m00.y, a.y, fmaf(m01.x, b.x, -m01.y * b.y)));
    na.y = fmaf(m00.x, a.y, fmaf( m00.y, a.x, fmaf(m01.x, b.y,  m01.y * b.x)));
    nb.x = fmaf(m10.x, a.x, fmaf(-m10.y, a.y, fmaf(m11.x, b.x, -m11.y * b.y)));
    nb.y = fmaf(m10.x, a.y, fmaf( m10.y, a.x, fmaf(m11.x, b.y,  m11.y * b.x)));
    a = na; b = nb;
}

// cross-lane xor exchange: DPP quad_perm for masks 1,2 (VALU pipe), shfl otherwise
template<int B>
__device__ __forceinline__ float shflx(float x) {
    if constexpr (B == 0) {
        int i = __float_as_int(x);
        return __int_as_float(__builtin_amdgcn_update_dpp(i, i, 0xB1, 0xF, 0xF, true)); // quad_perm 1,0,3,2
    } else if constexpr (B == 1) {
        int i = __float_as_int(x);
        return __int_as_float(__builtin_amdgcn_update_dpp(i, i, 0x4E, 0xF, 0xF, true)); // quad_perm 2,3,0,1
    } else {
        return __shfl_xor(x, 1 << B, 64);
    }
}

// gate M on register bit J (z bit 8+J): pure VALU
template<int J>
__device__ __forceinline__ void reg_gate(float2* v,
        const float2 m00, const float2 m01, const float2 m10, const float2 m11) {
#pragma unroll
    for (int m = 0; m < 8; ++m) {
        int r0 = ((m >> J) << (J + 1)) | (m & ((1 << J) - 1));
        cgate(v[r0], v[r0 | (1 << J)], m00, m01, m10, m11);
    }
}

// gate M on lane bit B (z bit B): cross-lane, no barrier
template<int B>
__device__ __forceinline__ void lane_gate(float2* v, int lane,
        const float2 m00, const float2 m01, const float2 m10, const float2 m11) {
    const bool hib = (lane >> B) & 1;
    const float cax = hib ? m11.x : m00.x, cay = hib ? m11.y : m00.y;
    const float cbx = hib ? m10.x : m01.x, cby = hib ? m10.y : m01.y;
#pragma unroll
    for (int r = 0; r < 16; ++r) {
        float px = shflx<B>(v[r].x);
        float py = shflx<B>(v[r].y);
        float nx = fmaf(cax, v[r].x, fmaf(-cay, v[r].y, fmaf(cbx, px, -cby * py)));
        float ny = fmaf(cax, v[r].y, fmaf( cay, v[r].x, fmaf(cbx, py,  cby * px)));
        v[r] = make_float2(nx, ny);
    }
}

// fused: gates on wave bits 6,7 (M on each) + Gray CNOT permutation new[z]=old[z^(z>>1)],
// one LDS round trip. NO local arrays / pointer selects (SROA-safe).
__device__ __forceinline__ void exchange(float2* psis, float2* v, int tid, int wv, int gwoff,
        const float2 m00, const float2 m01, const float2 m10, const float2 m11) {
    __syncthreads();                 // protect prior readers of psis
#pragma unroll
    for (int r = 0; r < 16; ++r) psis[(r << 8) | tid] = v[r];
    __syncthreads();

    const int y6  = (wv ^ (wv >> 1)) & 1;      // g(z) bit6 (same for all r)
    const int y7A = (wv >> 1) & 1;             // g(z) bit7 for even r; odd r flips
    const float2 M7A0 = y7A ? m10 : m00, M7A1 = y7A ? m11 : m01;
    const float2 M7B0 = y7A ? m00 : m10, M7B1 = y7A ? m01 : m11;
    const float2 M60  = y6  ? m10 : m00, M61  = y6  ? m11 : m01;
    // scalar row coefficients (even r -> A, odd r -> B)
    const float2 a0 = cmul(M7A0, M60), a1 = cmul(M7A0, M61), a2 = cmul(M7A1, M60), a3 = cmul(M7A1, M61);
    const float2 c0 = cmul(M7B0, M60), c1 = cmul(M7B0, M61), c2 = cmul(M7B1, M60), c3 = cmul(M7B1, M61);

#pragma unroll
    for (int h = 0; h < 8; ++h) {
        const int re = h << 1;
        const int baseE = ((((re << 8) ^ (re << 7)) ^ gwoff) & ~0xC0);
        const int baseO = baseE ^ 0x100;       // odd r differs by bit8 after masking
        float2 e0 = psis[baseE],        e1 = psis[baseE | 0x40];
        float2 e2 = psis[baseE | 0x80], e3 = psis[baseE | 0xC0];
        v[re]     = cfma4(a0, e0, a1, e1, a2, e2, a3, e3);
        float2 o0 = psis[baseO],        o1 = psis[baseO | 0x40];
        float2 o2 = psis[baseO | 0x80], o3 = psis[baseO | 0xC0];
        v[re | 1] = cfma4(c0, o0, c1, o1, c2, o2, c3, o3);
    }
}

// waves_per_eu(4,4): pin occupancy target to exactly 4 waves/EU (16 waves/CU = the
// LDS limit at 32.5 KB/block). R3 showed launch_bounds(256,4) lets the backend aim
// for 8 waves/EU -> 64-VGPR squeeze -> 140 MB of scratch spill traffic.
__global__ __launch_bounds__(TPB) __attribute__((amdgpu_waves_per_eu(4, 4)))
void qmnist_kernel(const float* __restrict__ x,  const float* __restrict__ W1,
                   const float* __restrict__ b1, const float* __restrict__ ryp,
                   const float* __restrict__ rzp, const float* __restrict__ W2,
                   const float* __restrict__ b2, float* __restrict__ out) {
    __shared__ float2 psis[DIM];
    __shared__ float  wred[4 * NW];
    __shared__ float  encc[NW], encs[NW];
    __shared__ float  zfin[NW];

    const int tid  = threadIdx.x;
    const int blk  = blockIdx.x;
    const int lane = tid & 63;
    const int wave = tid >> 6;
    const int wv   = tid >> 6;                  // z bits 7:6
    const int gwoff = tid ^ (tid >> 1);         // Gray of low-8 index bits

    // ---------------- phase 0: feat = x[blk] @ W1^T + b1 -> encoding angles
    float acc[NW];
#pragma unroll
    for (int w = 0; w < NW; ++w) acc[w] = 0.f;
    const float* xrow = x + (size_t)blk * 784;
    for (int j = tid; j < 784; j += TPB) {
        float xv = xrow[j];
#pragma unroll
        for (int w = 0; w < NW; ++w)
            acc[w] = fmaf(xv, W1[w * 784 + j], acc[w]);
    }
#pragma unroll
    for (int w = 0; w < NW; ++w) {
        float s = acc[w];
        s += __shfl_down(s, 32);
        s += __shfl_down(s, 16);
        s += __shfl_down(s, 8);
        s += __shfl_down(s, 4);
        s += __shfl_down(s, 2);
        s += __shfl_down(s, 1);
        if (lane == 0) wred[wave * NW + w] = s;
    }
    __syncthreads();
    if (tid < NW) {
        float feat = wred[tid] + wred[NW + tid] + wred[2 * NW + tid] + wred[3 * NW + tid] + b1[tid];
        float a = tanhf(feat) * 3.14159265358979323846f;
        float h = 0.5f * a;
        encc[tid] = cosf(h);
        encs[tid] = sinf(h);
    }
    __syncthreads();

    // ---------------- init product state directly into registers
    // z = (r<<8) | tid ; z bit b <-> wire (11-b)
    float hi = 1.f;
#pragma unroll
    for (int b = 0; b < 8; ++b) {
        int w = 11 - b;
        hi *= ((tid >> b) & 1) ? encs[w] : encc[w];
    }
    float2 v[16];
#pragma unroll
    for (int r = 0; r < 16; ++r) {
        float f = hi;
        f *= (r & 1) ? encs[3] : encc[3];
        f *= (r & 2) ? encs[2] : encc[2];
        f *= (r & 4) ? encs[1] : encc[1];
        f *= (r & 8) ? encs[0] : encc[0];
        v[r] = make_float2(f, 0.f);
    }

    // ---------------- fused variational gate  M = RZ(rz) * RY(ry)
    const float ry = ryp[0], rz = rzp[0];
    const float c  = cosf(0.5f * ry), s  = sinf(0.5f * ry);
    const float zc = cosf(0.5f * rz), zs = sinf(0.5f * rz);
    const float2 m00 = make_float2( c * zc, -c * zs);
    const float2 m01 = make_float2(-s * zc,  s * zs);
    const float2 m10 = make_float2( s * zc,  s * zs);
    const float2 m11 = make_float2( c * zc,  c * zs);

    for (int layer = 0; layer < 3; ++layer) {
        // register-bit gates (z bits 8..11), pure VALU
        reg_gate<0>(v, m00, m01, m10, m11);
        reg_gate<1>(v, m00, m01, m10, m11);
        reg_gate<2>(v, m00, m01, m10, m11);
        reg_gate<3>(v, m00, m01, m10, m11);
        // lane-bit gates (z bits 0..5), DPP / shuffle, no barriers
        lane_gate<0>(v, lane, m00, m01, m10, m11);
        lane_gate<1>(v, lane, m00, m01, m10, m11);
        lane_gate<2>(v, lane, m00, m01, m10, m11);
        lane_gate<3>(v, lane, m00, m01, m10, m11);
        lane_gate<4>(v, lane, m00, m01, m10, m11);
        lane_gate<5>(v, lane, m00, m01, m10, m11);
        // wave-bit gates (z bits 6,7) + Gray permutation, one LDS round trip
        exchange(psis, v, tid, wv, gwoff, m00, m01, m10, m11);
    }

    // ---------------- measure <Z_w>; state is in registers
    float t_total = 0.f, sj0 = 0.f, sj1 = 0.f, sj2 = 0.f, sj3 = 0.f;
#pragma unroll
    for (int r = 0; r < 16; ++r) {
        float p = fmaf(v[r].x, v[r].x, v[r].y * v[r].y);
        t_total += p;
        if (r & 1) sj0 += p;   // z bit 8  -> wire 3
        if (r & 2) sj1 += p;   // z bit 9  -> wire 2
        if (r & 4) sj2 += p;   // z bit 10 -> wire 1
        if (r & 8) sj3 += p;   // z bit 11 -> wire 0
    }
    float contrib[NW];
    contrib[3] = t_total - 2.f * sj0;
    contrib[2] = t_total - 2.f * sj1;
    contrib[1] = t_total - 2.f * sj2;
    contrib[0] = t_total - 2.f * sj3;
#pragma unroll
    for (int b = 0; b < 8; ++b) {
        int w = 11 - b;                      // wires 11..4 from tid bits 0..7
        contrib[w] = ((tid >> b) & 1) ? -t_total : t_total;
    }
#pragma unroll
    for (int w = 0; w < NW; ++w) {
        float sv = contrib[w];
        sv += __shfl_down(sv, 32);
        sv += __shfl_down(sv, 16);
        sv += __shfl_down(sv, 8);
        sv += __shfl_down(sv, 4);
        sv += __shfl_down(sv, 2);
        sv += __shfl_down(sv, 1);
        if (lane == 0) wred[wave * NW + w] = sv;
    }
    __syncthreads();
    if (tid < NW)
        zfin[tid] = wred[tid] + wred[NW + tid] + wred[2 * NW + tid] + wred[3 * NW + tid];
    __syncthreads();

    // ---------------- head: out = z @ W2^T + b2
    if (tid < 10) {
        float o = b2[tid];
#pragma unroll
        for (int w = 0; w < NW; ++w)
            o = fmaf(zfin[w], W2[tid * NW + w], o);
        out[(size_t)blk * 10 + tid] = o;
    }
}

extern "C" void kernel_launch(void* const* d_in, const int* in_sizes, int n_in,
                              void* d_out, int out_size, void* d_ws, size_t ws_size,
                              hipStream_t stream) {
    const float* x   = (const float*)d_in[0];
    const float* W1  = (const float*)d_in[1];
    const float* b1  = (const float*)d_in[2];
    const float* ry  = (const float*)d_in[3];
    const float* rz  = (const float*)d_in[4];
    const float* W2  = (const float*)d_in[5];
    const float* b2  = (const float*)d_in[6];
    float* out = (float*)d_out;

    const int batch = in_sizes[0] / 784;   // 2048
    qmnist_kernel<<<batch, TPB, 0, stream>>>(x, W1, b1, ry, rz, W2, b2, out);
}

// Round 5
// 161.768 us; speedup vs baseline: 1.1623x; 1.1595x over previous
//
#include <hip/hip_runtime.h>
#include <math.h>

#define NW   12
#define DIM  4096
#define TPB  256

// force a wave-uniform float into an SGPR (drops VGPR pressure; v_fma takes 1 SGPR src)
__device__ __forceinline__ float rfl(float f) {
    return __int_as_float(__builtin_amdgcn_readfirstlane(__float_as_int(f)));
}
__device__ __forceinline__ float2 rfl2(float2 f) { return make_float2(rfl(f.x), rfl(f.y)); }

__device__ __forceinline__ float2 cmul(float2 a, float2 b) {
    return make_float2(a.x * b.x - a.y * b.y, a.x * b.y + a.y * b.x);
}

// acc = sum_j c_j * x_j (complex), 4 terms, no arrays (SROA-safe)
__device__ __forceinline__ float2 cfma4(float2 c0, float2 x0, float2 c1, float2 x1,
                                        float2 c2, float2 x2, float2 c3, float2 x3) {
    float ax = 0.f, ay = 0.f;
    ax = fmaf(c0.x, x0.x, fmaf(-c0.y, x0.y, ax)); ay = fmaf(c0.x, x0.y, fmaf(c0.y, x0.x, ay));
    ax = fmaf(c1.x, x1.x, fmaf(-c1.y, x1.y, ax)); ay = fmaf(c1.x, x1.y, fmaf(c1.y, x1.x, ay));
    ax = fmaf(c2.x, x2.x, fmaf(-c2.y, x2.y, ax)); ay = fmaf(c2.x, x2.y, fmaf(c2.y, x2.x, ay));
    ax = fmaf(c3.x, x3.x, fmaf(-c3.y, x3.y, ax)); ay = fmaf(c3.x, x3.y, fmaf(c3.y, x3.x, ay));
    return make_float2(ax, ay);
}

// (a,b) <- M (a,b), complex 2x2 (M components expected in SGPRs)
__device__ __forceinline__ void cgate(float2& a, float2& b,
        const float2 m00, const float2 m01, const float2 m10, const float2 m11) {
    float2 na, nb;
    na.x = fmaf(m00.x, a.x, fmaf(-m00.y, a.y, fmaf(m01.x, b.x, -m01.y * b.y)));
    na.y = fmaf(m00.x, a.y, fmaf( m00.y, a.x, fmaf(m01.x, b.y,  m01.y * b.x)));
    nb.x = fmaf(m10.x, a.x, fmaf(-m10.y, a.y, fmaf(m11.x, b.x, -m11.y * b.y)));
    nb.y = fmaf(m10.x, a.y, fmaf( m10.y, a.x, fmaf(m11.x, b.y,  m11.y * b.x)));
    a = na; b = nb;
}

// cross-lane xor exchange: DPP quad_perm for masks 1,2 (VALU pipe), shfl otherwise
template<int B>
__device__ __forceinline__ float shflx(float x) {
    if constexpr (B == 0) {
        int i = __float_as_int(x);
        return __int_as_float(__builtin_amdgcn_update_dpp(i, i, 0xB1, 0xF, 0xF, true)); // quad_perm 1,0,3,2
    } else if constexpr (B == 1) {
        int i = __float_as_int(x);
        return __int_as_float(__builtin_amdgcn_update_dpp(i, i, 0x4E, 0xF, 0xF, true)); // quad_perm 2,3,0,1
    } else {
        return __shfl_xor(x, 1 << B, 64);
    }
}

// gate M on register bit J (z bit 8+J): pure VALU, coefficients in SGPRs
template<int J>
__device__ __forceinline__ void reg_gate(float2* v,
        const float2 m00, const float2 m01, const float2 m10, const float2 m11) {
#pragma unroll
    for (int m = 0; m < 8; ++m) {
        int r0 = ((m >> J) << (J + 1)) | (m & ((1 << J) - 1));
        cgate(v[r0], v[r0 | (1 << J)], m00, m01, m10, m11);
    }
}

// gate M on lane bit B (z bit B): cross-lane, no barrier
template<int B>
__device__ __forceinline__ void lane_gate(float2* v, int lane,
        const float2 m00, const float2 m01, const float2 m10, const float2 m11) {
    const bool hib = (lane >> B) & 1;
    const float cax = hib ? m11.x : m00.x, cay = hib ? m11.y : m00.y;
    const float cbx = hib ? m10.x : m01.x, cby = hib ? m10.y : m01.y;
#pragma unroll
    for (int r = 0; r < 16; ++r) {
        float px = shflx<B>(v[r].x);
        float py = shflx<B>(v[r].y);
        float nx = fmaf(cax, v[r].x, fmaf(-cay, v[r].y, fmaf(cbx, px, -cby * py)));
        float ny = fmaf(cax, v[r].y, fmaf( cay, v[r].x, fmaf(cbx, py,  cby * px)));
        v[r] = make_float2(nx, ny);
    }
}

// fused: gates on wave bits 6,7 (M on each) + Gray CNOT permutation new[z]=old[z^(z>>1)],
// one LDS round trip. Row coefficients are wave-uniform -> pinned to SGPRs via rfl2.
__device__ __forceinline__ void exchange(float2* psis, float2* v, int tid, int wv, int gwoff,
        const float2 m00, const float2 m01, const float2 m10, const float2 m11) {
    __syncthreads();                 // protect prior readers of psis
#pragma unroll
    for (int r = 0; r < 16; ++r) psis[(r << 8) | tid] = v[r];
    __syncthreads();

    const int y6  = (wv ^ (wv >> 1)) & 1;      // g(z) bit6 (same for all r)
    const int y7A = (wv >> 1) & 1;             // g(z) bit7 for even r; odd r flips
    const float2 M7A0 = y7A ? m10 : m00, M7A1 = y7A ? m11 : m01;
    const float2 M7B0 = y7A ? m00 : m10, M7B1 = y7A ? m01 : m11;
    const float2 M60  = y6  ? m10 : m00, M61  = y6  ? m11 : m01;
    // wave-uniform row coefficients -> SGPRs (even r -> a*, odd r -> c*)
    const float2 a0 = rfl2(cmul(M7A0, M60)), a1 = rfl2(cmul(M7A0, M61));
    const float2 a2 = rfl2(cmul(M7A1, M60)), a3 = rfl2(cmul(M7A1, M61));
    const float2 c0 = rfl2(cmul(M7B0, M60)), c1 = rfl2(cmul(M7B0, M61));
    const float2 c2 = rfl2(cmul(M7B1, M60)), c3 = rfl2(cmul(M7B1, M61));

#pragma unroll
    for (int h = 0; h < 8; ++h) {
        const int re = h << 1;
        const int baseE = ((((re << 8) ^ (re << 7)) ^ gwoff) & ~0xC0);
        const int baseO = baseE ^ 0x100;       // odd r differs by bit8 after masking
        float2 e0 = psis[baseE],        e1 = psis[baseE | 0x40];
        float2 e2 = psis[baseE | 0x80], e3 = psis[baseE | 0xC0];
        v[re]     = cfma4(a0, e0, a1, e1, a2, e2, a3, e3);
        float2 o0 = psis[baseO],        o1 = psis[baseO | 0x40];
        float2 o2 = psis[baseO | 0x80], o3 = psis[baseO | 0xC0];
        v[re | 1] = cfma4(c0, o0, c1, o1, c2, o2, c3, o3);
    }
}

__global__ __launch_bounds__(TPB, 4)
void qmnist_kernel(const float* __restrict__ x,  const float* __restrict__ W1,
                   const float* __restrict__ b1, const float* __restrict__ ryp,
                   const float* __restrict__ rzp, const float* __restrict__ W2,
                   const float* __restrict__ b2, float* __restrict__ out) {
    __shared__ float2 psis[DIM];
    __shared__ float  wred[4 * NW];
    __shared__ float  encc[NW], encs[NW];
    __shared__ float  zfin[NW];

    const int tid  = threadIdx.x;
    const int blk  = blockIdx.x;
    const int lane = tid & 63;
    const int wave = tid >> 6;
    const int wv   = tid >> 6;                  // z bits 7:6
    const int gwoff = tid ^ (tid >> 1);         // Gray of low-8 index bits

    // ---------------- phase 0: feat = x[blk] @ W1^T + b1 -> encoding angles
    float acc[NW];
#pragma unroll
    for (int w = 0; w < NW; ++w) acc[w] = 0.f;
    const float* xrow = x + (size_t)blk * 784;
    for (int j = tid; j < 784; j += TPB) {
        float xv = xrow[j];
#pragma unroll
        for (int w = 0; w < NW; ++w)
            acc[w] = fmaf(xv, W1[w * 784 + j], acc[w]);
    }
#pragma unroll
    for (int w = 0; w < NW; ++w) {
        float s = acc[w];
        s += __shfl_down(s, 32);
        s += __shfl_down(s, 16);
        s += __shfl_down(s, 8);
        s += __shfl_down(s, 4);
        s += __shfl_down(s, 2);
        s += __shfl_down(s, 1);
        if (lane == 0) wred[wave * NW + w] = s;
    }
    __syncthreads();
    if (tid < NW) {
        float feat = wred[tid] + wred[NW + tid] + wred[2 * NW + tid] + wred[3 * NW + tid] + b1[tid];
        float a = tanhf(feat) * 3.14159265358979323846f;
        float h = 0.5f * a;
        encc[tid] = cosf(h);
        encs[tid] = sinf(h);
    }
    __syncthreads();

    // ---------------- init product state directly into registers
    // z = (r<<8) | tid ; z bit b <-> wire (11-b)
    float hi = 1.f;
#pragma unroll
    for (int b = 0; b < 8; ++b) {
        int w = 11 - b;
        hi *= ((tid >> b) & 1) ? encs[w] : encc[w];
    }
    float2 v[16];
#pragma unroll
    for (int r = 0; r < 16; ++r) {
        float f = hi;
        f *= (r & 1) ? encs[3] : encc[3];
        f *= (r & 2) ? encs[2] : encc[2];
        f *= (r & 4) ? encs[1] : encc[1];
        f *= (r & 8) ? encs[0] : encc[0];
        v[r] = make_float2(f, 0.f);
    }

    // ---------------- fused variational gate  M = RZ(rz) * RY(ry)
    // all 8 coefficient floats are grid-uniform -> pin to SGPRs
    const float ry = ryp[0], rz = rzp[0];
    const float c  = cosf(0.5f * ry), s  = sinf(0.5f * ry);
    const float zc = cosf(0.5f * rz), zs = sinf(0.5f * rz);
    const float2 m00 = rfl2(make_float2( c * zc, -c * zs));
    const float2 m01 = rfl2(make_float2(-s * zc,  s * zs));
    const float2 m10 = rfl2(make_float2( s * zc,  s * zs));
    const float2 m11 = rfl2(make_float2( c * zc,  c * zs));

    for (int layer = 0; layer < 3; ++layer) {
        // register-bit gates (z bits 8..11), pure VALU
        reg_gate<0>(v, m00, m01, m10, m11);
        reg_gate<1>(v, m00, m01, m10, m11);
        reg_gate<2>(v, m00, m01, m10, m11);
        reg_gate<3>(v, m00, m01, m10, m11);
        // lane-bit gates (z bits 0..5), DPP / shuffle, no barriers
        lane_gate<0>(v, lane, m00, m01, m10, m11);
        lane_gate<1>(v, lane, m00, m01, m10, m11);
        lane_gate<2>(v, lane, m00, m01, m10, m11);
        lane_gate<3>(v, lane, m00, m01, m10, m11);
        lane_gate<4>(v, lane, m00, m01, m10, m11);
        lane_gate<5>(v, lane, m00, m01, m10, m11);
        // wave-bit gates (z bits 6,7) + Gray permutation, one LDS round trip
        exchange(psis, v, tid, wv, gwoff, m00, m01, m10, m11);
    }

    // ---------------- measure <Z_w>; state is in registers
    float t_total = 0.f, sj0 = 0.f, sj1 = 0.f, sj2 = 0.f, sj3 = 0.f;
#pragma unroll
    for (int r = 0; r < 16; ++r) {
        float p = fmaf(v[r].x, v[r].x, v[r].y * v[r].y);
        t_total += p;
        if (r & 1) sj0 += p;   // z bit 8  -> wire 3
        if (r & 2) sj1 += p;   // z bit 9  -> wire 2
        if (r & 4) sj2 += p;   // z bit 10 -> wire 1
        if (r & 8) sj3 += p;   // z bit 11 -> wire 0
    }
    float contrib[NW];
    contrib[3] = t_total - 2.f * sj0;
    contrib[2] = t_total - 2.f * sj1;
    contrib[1] = t_total - 2.f * sj2;
    contrib[0] = t_total - 2.f * sj3;
#pragma unroll
    for (int b = 0; b < 8; ++b) {
        int w = 11 - b;                      // wires 11..4 from tid bits 0..7
        contrib[w] = ((tid >> b) & 1) ? -t_total : t_total;
    }
#pragma unroll
    for (int w = 0; w < NW; ++w) {
        float sv = contrib[w];
        sv += __shfl_down(sv, 32);
        sv += __shfl_down(sv, 16);
        sv += __shfl_down(sv, 8);
        sv += __shfl_down(sv, 4);
        sv += __shfl_down(sv, 2);
        sv += __shfl_down(sv, 1);
        if (lane == 0) wred[wave * NW + w] = sv;
    }
    __syncthreads();
    if (tid < NW)
        zfin[tid] = wred[tid] + wred[NW + tid] + wred[2 * NW + tid] + wred[3 * NW + tid];
    __syncthreads();

    // ---------------- head: out = z @ W2^T + b2
    if (tid < 10) {
        float o = b2[tid];
#pragma unroll
        for (int w = 0; w < NW; ++w)
            o = fmaf(zfin[w], W2[tid * NW + w], o);
        out[(size_t)blk * 10 + tid] = o;
    }
}

extern "C" void kernel_launch(void* const* d_in, const int* in_sizes, int n_in,
                              void* d_out, int out_size, void* d_ws, size_t ws_size,
                              hipStream_t stream) {
    const float* x   = (const float*)d_in[0];
    const float* W1  = (const float*)d_in[1];
    const float* b1  = (const float*)d_in[2];
    const float* ry  = (const float*)d_in[3];
    const float* rz  = (const float*)d_in[4];
    const float* W2  = (const float*)d_in[5];
    const float* b2  = (const float*)d_in[6];
    float* out = (float*)d_out;

    const int batch = in_sizes[0] / 784;   // 2048
    qmnist_kernel<<<batch, TPB, 0, stream>>>(x, W1, b1, ry, rz, W2, b2, out);
}